// Round 21
// baseline (210.121 us; speedup 1.0000x reference)
//
#include <hip/hip_runtime.h>

typedef float f4v __attribute__((ext_vector_type(4)));
typedef _Float16 h8 __attribute__((ext_vector_type(8)));
typedef _Float16 h4 __attribute__((ext_vector_type(4)));
typedef _Float16 h2 __attribute__((ext_vector_type(2)));
typedef __fp16 f16x2 __attribute__((ext_vector_type(2)));

// Problem constants
// C=192, NH=8, DH=24, window 6x8x8 -> N=384 tokens, D/H/W = 24/64/64 -> 256 windows
// shift (3,4,4). Spatial stride per channel = 24*64*64 = 98304.
// Staging layout (f16): [head][win][n][24]  -> slab (head,win) = 384*24 = 9216 elems.
// PO staging (f16): [win][n][192] (aliased onto Qs — dead after attn).

__device__ __forceinline__ float fast_exp2(float x) {
#if __has_builtin(__builtin_amdgcn_exp2f)
    return __builtin_amdgcn_exp2f(x);
#else
    return exp2f(x);
#endif
}
__device__ __forceinline__ float fast_rcp(float x) {
#if __has_builtin(__builtin_amdgcn_rcpf)
    return __builtin_amdgcn_rcpf(x);
#else
    return 1.0f / x;
#endif
}

// region slot for token n (3-bit: d,h,w boundary crossing), block-uniform wi/hi/wj
__device__ __forceinline__ int region_slot(int n, int wi, int hi, int wj) {
    int s = 0;
    if (wi == 3 && (n >> 6) >= 3) s += 4;
    if (hi == 7 && ((n >> 3) & 7) >= 4) s += 2;
    if (wj == 7 && (n & 7) >= 4) s += 1;
    return s;
}

// ---------------------------------------------------------------------------
// Kernel 1: transpose + roll + window-partition + LayerNorm -> f16 staging.
// r21: duty-cycle fix. r20 showed MLP wasn't binding; the limit is phase
// alternation (load-burst / LDS-idle) with only 3 resident blocks/CU.
//  - psum/psq [16][64] (8KB) -> per-wave shfl_xor(16/32) reduce over the 4
//    c0-groups, tiny [4][64] partials (2KB).
//  - tile pad 68 -> 70: 48*pad was === 0 mod 32 -> all 4 p-groups same bank
//    (8-way) in phase 3; pad 70 makes it <=2-way.
//  - LDS ~31KB -> 4-5 blocks/CU: neighbor blocks' phases overlap.
// ---------------------------------------------------------------------------
__global__ __launch_bounds__(256) void ln_stage_kernel(
    const float* __restrict__ q, const float* __restrict__ k, const float* __restrict__ v,
    const float* __restrict__ nqw, const float* __restrict__ nqb,
    const float* __restrict__ nkw, const float* __restrict__ nkb,
    _Float16* __restrict__ Qs, _Float16* __restrict__ Ks, _Float16* __restrict__ Vs)
{
    const int tid = threadIdx.x;
    const int bid = blockIdx.x;      // d*64 + h
    const int tensor = blockIdx.y;   // 0=q, 1=k, 2=v
    const int d = bid >> 6;
    const int h = bid & 63;

    const float* src = (tensor == 0) ? q : (tensor == 1) ? k : v;
    const float* gam = (tensor == 0) ? nqw : nkw;
    const float* bet = (tensor == 0) ? nqb : nkb;
    _Float16* dst = (tensor == 0) ? Qs : (tensor == 1) ? Ks : Vs;
    // fold softmax scale (1/sqrt(24)) and log2(e) into Q so scores are in exp2 domain
    const float scale = (tensor == 0) ? (0.20412414523193154f * 1.44269504088896340f) : 1.0f;

    __shared__ __attribute__((aligned(16))) _Float16 tile[192][70];
    __shared__ __attribute__((aligned(16))) float psum4[4][64];
    __shared__ __attribute__((aligned(16))) float psq4[4][64];
    __shared__ float smean[64];
    __shared__ float srstd[64];
    __shared__ float sgam[192];
    __shared__ float sbet[192];

    if (tid < 192) { sgam[tid] = gam[tid]; sbet[tid] = bet[tid]; }

    const int lane = tid & 63;
    const int wid = tid >> 6;
    const int c0 = tid >> 4;           // 0..15
    const int col = (tid & 15) << 2;   // 0..60

    // phase 1a: issue ALL 12 coalesced loads (registers; 48 VGPR in flight)
    f4v xr[12];
    {
        const float* base = src + (size_t)d * 4096 + (size_t)h * 64 + col;
        #pragma unroll
        for (int r = 0; r < 12; ++r)
            xr[r] = *(const f4v*)(base + (size_t)(r * 16 + c0) * 98304);
    }
#if __has_builtin(__builtin_amdgcn_sched_barrier)
    __builtin_amdgcn_sched_barrier(0);
#endif
    asm volatile("" ::
        "v"(xr[0]), "v"(xr[1]), "v"(xr[2]), "v"(xr[3]),
        "v"(xr[4]), "v"(xr[5]), "v"(xr[6]), "v"(xr[7]),
        "v"(xr[8]), "v"(xr[9]), "v"(xr[10]), "v"(xr[11]));

    // phase 1b: partials + f16 tile; wave-level reduce over the 4 c0s/wave
    {
        f4v s4 = {}, ss4 = {};
        #pragma unroll
        for (int r = 0; r < 12; ++r) {
            f4v x = xr[r];
            s4 += x;
            ss4 += x * x;
            h4 hx;
            hx[0] = (_Float16)x[0]; hx[1] = (_Float16)x[1];
            hx[2] = (_Float16)x[2]; hx[3] = (_Float16)x[3];
            *(h4*)&tile[r * 16 + c0][col] = hx;
        }
        #pragma unroll
        for (int m = 0; m < 4; ++m) {
            s4[m] += __shfl_xor(s4[m], 16);  s4[m] += __shfl_xor(s4[m], 32);
            ss4[m] += __shfl_xor(ss4[m], 16); ss4[m] += __shfl_xor(ss4[m], 32);
        }
        if (lane < 16) {
            *(f4v*)&psum4[wid][lane * 4] = s4;
            *(f4v*)&psq4[wid][lane * 4] = ss4;
        }
    }
    __syncthreads();

    // phase 2: combine 4 per-wave partials per token
    if (tid < 64) {
        float S = psum4[0][tid] + psum4[1][tid] + psum4[2][tid] + psum4[3][tid];
        float SS = psq4[0][tid] + psq4[1][tid] + psq4[2][tid] + psq4[3][tid];
        float mean = S * (1.0f / 192.0f);
        float var = SS * (1.0f / 192.0f) - mean * mean;
        smean[tid] = mean;
        srstd[tid] = rsqrtf(var + 1e-5f);
    }
    __syncthreads();

    // phase 3: normalize + write f16 staging, head-major: [head][win][n][24]
    {
        const int wpos = tid >> 2;   // 0..63 source w
        const int p = tid & 3;       // channel quarter = heads 2p, 2p+1
        const float mean = smean[wpos];
        const float rstd = srstd[wpos];
        int d_r = d + 21; if (d_r >= 24) d_r -= 24;
        int h_r = h + 60; if (h_r >= 64) h_r -= 64;
        int w_r = wpos + 60; if (w_r >= 64) w_r -= 64;
        const int wi = d_r / 6, td = d_r - wi * 6;
        const int hi = h_r >> 3, th = h_r & 7;
        const int wj = w_r >> 3, tw = w_r & 7;
        const int win = (wi * 8 + hi) * 8 + wj;
        const int n = (td * 8 + th) * 8 + tw;
        #pragma unroll
        for (int hh2 = 0; hh2 < 2; ++hh2) {
            const int head = p * 2 + hh2;
            _Float16* outp = dst + (size_t)(head * 256 + win) * 9216 + n * 24;
            #pragma unroll
            for (int cc = 0; cc < 3; ++cc) {
                const int c = head * 24 + cc * 8;
                h8 hv;
                #pragma unroll
                for (int j = 0; j < 8; ++j) {
                    float x = ((float)tile[c + j][wpos] - mean) * rstd * sgam[c + j] + sbet[c + j];
                    hv[j] = (_Float16)(x * scale);
                }
                *(h8*)(outp + cc * 8) = hv;
            }
        }
    }
}

// ---------------------------------------------------------------------------
// Kernel 2: proj_w f32 -> f16
// ---------------------------------------------------------------------------
__global__ __launch_bounds__(256) void wconv_kernel(const float* __restrict__ w,
                                                    _Float16* __restrict__ wb)
{
    int i = blockIdx.x * 256 + threadIdx.x;
    if (i < 192 * 192) wb[i] = (_Float16)w[i];
}

// ---------------------------------------------------------------------------
// attn epilogue: rowsum comes FREE from o1's duplicate lanes (l15>=8 read the
// ones-row) -> inv via one shfl per j. Wave-private Ob sub-tile; per-wave DS
// ordering + lgkmcnt fence (proven r4+).
// ---------------------------------------------------------------------------
__device__ __forceinline__ void attn_epilogue(
    f4v o0, f4v o1, _Float16* __restrict__ Op,
    _Float16* __restrict__ AOw, int q0, int lane, int l15, int g)
{
    #pragma unroll
    for (int j = 0; j < 4; ++j) {
        float rs = __shfl(o1[j], (g << 4) | 8);   // lane l15=8 of this g holds rowsum
        float inv = fast_rcp(rs);
        const int r = 4 * g + j;
        Op[r * 24 + l15] = (_Float16)(o0[j] * inv);
        if (l15 < 8) Op[r * 24 + 16 + l15] = (_Float16)(o1[j] * inv);
    }
    asm volatile("s_waitcnt lgkmcnt(0)" ::: "memory");
    // coalesced 768B burst: 48 lanes x 16B contiguous
    if (lane < 48) {
        h8 ov = *(const h8*)(Op + lane * 8);
        *(h8*)(AOw + (size_t)q0 * 24 + lane * 8) = ov;
    }
    asm volatile("" ::: "memory");
}

// ---------------------------------------------------------------------------
// Kernel 3: windowed attention, one block per (window, head). 8 WAVES (512t).
// r17 structure (unchanged): region-channel masking in the K=32 pad (one-hot
// * sqrt(40), cinit -46 -> masked p == 0 in f16); rowsum via ones-row in o1's
// duplicate lanes; 2+1 split fusion (pass A fuses qt{0,1}, pass B = qt2,
// pass-A AO stores hide under pass B). VGPR ~124 at (512,2) — do not perturb.
// ---------------------------------------------------------------------------
__global__ __launch_bounds__(512, 2) void attn_kernel(
    const _Float16* __restrict__ Qs, const _Float16* __restrict__ Ks,
    const _Float16* __restrict__ Vs, _Float16* __restrict__ AOs)
{
    const int win = blockIdx.x;
    const int head = blockIdx.y;
    const int tid = threadIdx.x;
    const int lane = tid & 63;
    const int wid = tid >> 6;        // 0..7
    const int l15 = lane & 15;
    const int g = lane >> 4;

    __shared__ __attribute__((aligned(16))) _Float16 Kh[384 * 36];      // [token][36]: dh0..23, onehot 24..31, pad
    __shared__ __attribute__((aligned(16))) _Float16 Vt[25 * 388];      // [dh][token pad388]; row 24 = ones
    __shared__ __attribute__((aligned(16))) _Float16 Ob[8][2][16 * 24]; // per-wave, qt-parity dbuf

    const int wi = win >> 6, hi = (win >> 3) & 7, wj = win & 7;

    const size_t slab = (size_t)(head * 256 + win) * 9216;
    const _Float16* Kw = Ks + slab;
    const _Float16* Vw = Vs + slab;
    const _Float16* Qw = Qs + slab;
    _Float16* AOw = AOs + slab;

    const _Float16 mreg = (_Float16)6.32455532f;   // sqrt(40)

    // ---- hoist this wave's 3 Q fragments; g==3 = one-hot(region(q)) * m ----
    h8 qreg[3];
    #pragma unroll
    for (int qt = 0; qt < 3; ++qt) {
        h8 z = {};
        if (g < 3) {
            z = *(const h8*)(Qw + (size_t)(wid * 48 + qt * 16 + l15) * 24 + g * 8);
        } else {
            int slot = region_slot(wid * 48 + qt * 16 + l15, wi, hi, wj);
            #pragma unroll
            for (int j = 0; j < 8; ++j) z[j] = (slot == j) ? mreg : (_Float16)0.f;
        }
        qreg[qt] = z;
    }

    // ---- stage K (36-wide rows + one-hot tails), V^T, ones-row ----
    {
        const h8* K8 = (const h8*)Kw;
        const h8* V8 = (const h8*)Vw;
        #pragma unroll
        for (int it = 0; it < 5; ++it) {
            int idx = it * 512 + tid;        // 0..2303 ; 0..1151 = K, 1152.. = V
            if (idx < 1152) {
                int n = idx / 3;
                int ch = idx - n * 3;
                *(h8*)(Kh + n * 36 + ch * 8) = K8[idx];
            } else if (idx < 2304) {
                int i = idx - 1152;          // flat h8 index in V slab
                int n = i / 3;               // token
                int ch = i - n * 3;          // 8-dh chunk
                h8 vv = V8[i];
                #pragma unroll
                for (int j = 0; j < 8; ++j) Vt[(ch * 8 + j) * 388 + n] = vv[j];
            }
        }
        if (tid < 384) {
            int slot = region_slot(tid, wi, hi, wj);
            h8 t;
            #pragma unroll
            for (int j = 0; j < 8; ++j) t[j] = (slot == j) ? mreg : (_Float16)0.f;
            *(h8*)(Kh + tid * 36 + 24) = t;
            Vt[24 * 388 + tid] = (_Float16)1.f;   // ones-row for rowsum
        }
    }
    __syncthreads();

    // lanes 0-7 of o1 -> dh 16-23; lanes 8-15 -> ones row (rowsum)
    const int v1row = (l15 < 8) ? (16 + l15) : 24;
    const int q0w = wid * 48;

    // ---- PASS A: fused qt0+qt1 mt loop (shared kf/v0/v1; 2 chains) ----
    f4v o0_0 = {}, o1_0 = {}, o0_1 = {}, o1_1 = {};
    #pragma unroll
    for (int mt = 0; mt < 24; ++mt) {
        h8 kf = *(const h8*)(Kh + (16 * mt + l15) * 36 + g * 8);
        h4 v0 = *(const h4*)(Vt + l15 * 388 + 16 * mt + 4 * g);
        h4 v1 = *(const h4*)(Vt + v1row * 388 + 16 * mt + 4 * g);
        const f4v cinit = {-46.f, -46.f, -46.f, -46.f};

        // qt0 chain
        {
            f4v s4 = __builtin_amdgcn_mfma_f32_16x16x32_f16(kf, qreg[0], cinit, 0, 0, 0);
            float p0 = fast_exp2(s4[0]), p1 = fast_exp2(s4[1]);
            float p2 = fast_exp2(s4[2]), p3 = fast_exp2(s4[3]);
            union { f16x2 gp[2]; h4 v; } pu;
            pu.gp[0] = __builtin_amdgcn_cvt_pkrtz(p0, p1);
            pu.gp[1] = __builtin_amdgcn_cvt_pkrtz(p2, p3);
            o0_0 = __builtin_amdgcn_mfma_f32_16x16x16f16(pu.v, v0, o0_0, 0, 0, 0);
            o1_0 = __builtin_amdgcn_mfma_f32_16x16x16f16(pu.v, v1, o1_0, 0, 0, 0);
        }
        // qt1 chain
        {
            f4v s4 = __builtin_amdgcn_mfma_f32_16x16x32_f16(kf, qreg[1], cinit, 0, 0, 0);
            float p0 = fast_exp2(s4[0]), p1 = fast_exp2(s4[1]);
            float p2 = fast_exp2(s4[2]), p3 = fast_exp2(s4[3]);
            union { f16x2 gp[2]; h4 v; } pu;
            pu.gp[0] = __builtin_amdgcn_cvt_pkrtz(p0, p1);
            pu.gp[1] = __builtin_amdgcn_cvt_pkrtz(p2, p3);
            o0_1 = __builtin_amdgcn_mfma_f32_16x16x16f16(pu.v, v0, o0_1, 0, 0, 0);
            o1_1 = __builtin_amdgcn_mfma_f32_16x16x16f16(pu.v, v1, o1_1, 0, 0, 0);
        }
    }

    // pass-A epilogues (AO stores issue now; latency hides under pass B)
    attn_epilogue(o0_0, o1_0, Ob[wid][0], AOw, q0w,      lane, l15, g);
    attn_epilogue(o0_1, o1_1, Ob[wid][1], AOw, q0w + 16, lane, l15, g);

    // ---- PASS B: qt2 alone (a/b acc split for dep-breaking) ----
    f4v o0a = {}, o0b = {}, o1a = {}, o1b = {};
    #pragma unroll
    for (int mt = 0; mt < 24; ++mt) {
        h8 kf = *(const h8*)(Kh + (16 * mt + l15) * 36 + g * 8);
        h4 v0 = *(const h4*)(Vt + l15 * 388 + 16 * mt + 4 * g);
        h4 v1 = *(const h4*)(Vt + v1row * 388 + 16 * mt + 4 * g);
        const f4v cinit = {-46.f, -46.f, -46.f, -46.f};
        f4v s4 = __builtin_amdgcn_mfma_f32_16x16x32_f16(kf, qreg[2], cinit, 0, 0, 0);
        float p0 = fast_exp2(s4[0]), p1 = fast_exp2(s4[1]);
        float p2 = fast_exp2(s4[2]), p3 = fast_exp2(s4[3]);
        union { f16x2 gp[2]; h4 v; } pu;
        pu.gp[0] = __builtin_amdgcn_cvt_pkrtz(p0, p1);
        pu.gp[1] = __builtin_amdgcn_cvt_pkrtz(p2, p3);
        if (mt & 1) {
            o0b = __builtin_amdgcn_mfma_f32_16x16x16f16(pu.v, v0, o0b, 0, 0, 0);
            o1b = __builtin_amdgcn_mfma_f32_16x16x16f16(pu.v, v1, o1b, 0, 0, 0);
        } else {
            o0a = __builtin_amdgcn_mfma_f32_16x16x16f16(pu.v, v0, o0a, 0, 0, 0);
            o1a = __builtin_amdgcn_mfma_f32_16x16x16f16(pu.v, v1, o1a, 0, 0, 0);
        }
    }
    attn_epilogue(o0a + o0b, o1a + o1b, Ob[wid][0], AOw, q0w + 32, lane, l15, g);
}

// ---------------------------------------------------------------------------
// Kernel 4: projection (X @ W^T + b) -> PO staging [win][n][192] f16.
// Each wave's 16-token tile = 6KB contiguous PO region written as 1KB/instr
// h8 bursts -> full-line HBM writes.
// ---------------------------------------------------------------------------
__global__ __launch_bounds__(256) void proj_kernel(
    const _Float16* __restrict__ AOs, const _Float16* __restrict__ Wb,
    const float* __restrict__ bias, _Float16* __restrict__ PO)
{
    const int bid = blockIdx.x;             // 0..1535
    const int win = bid / 6;
    const int r6 = bid - win * 6;
    const int half = r6 / 3;
    const int mi = r6 - half * 3;
    const int tid = threadIdx.x;
    const int lane = tid & 63, wid = tid >> 6;
    const int l15 = lane & 15, g = lane >> 4;

    __shared__ __attribute__((aligned(16))) float tileT[4][192 * 17];
    float* Tw = tileT[wid];

    const int tb = half * 192 + mi * 64 + wid * 16;

    // per-lane fragment -> (head, sub-chunk) decomposition for m = kk*4+g
    int hdk[6], sbk[6];
    #pragma unroll
    for (int kk = 0; kk < 6; ++kk) {
        int mm = kk * 4 + g;
        hdk[kk] = mm / 3;
        sbk[kk] = mm - 3 * hdk[kk];
    }

    // preload this wave's 6 A-fragments (16 tokens x 32 channels each)
    h8 af[6];
    #pragma unroll
    for (int kk = 0; kk < 6; ++kk)
        af[kk] = *(const h8*)(AOs + (size_t)(hdk[kk] * 256 + win) * 9216
                                  + (size_t)(tb + l15) * 24 + sbk[kk] * 8);

    // GEMM: n-outer, kk-inner (bounds live bf fragments; acc[n] hot)
    f4v acc[12];
    #pragma unroll
    for (int n = 0; n < 12; ++n) {
        f4v a = {};
        #pragma unroll
        for (int kk = 0; kk < 6; ++kk) {
            h8 bf = *(const h8*)(Wb + (size_t)(n * 16 + l15) * 192 + kk * 32 + g * 8);
            a = __builtin_amdgcn_mfma_f32_16x16x32_f16(af[kk], bf, a, 0, 0, 0);
        }
        acc[n] = a;
    }

    // bias + transpose through wave-private LDS ([c][token16] pad17)
    #pragma unroll
    for (int n = 0; n < 12; ++n) {
        float b = bias[n * 16 + l15];
        f4v vv = acc[n];
        vv[0] += b; vv[1] += b; vv[2] += b; vv[3] += b;
        *(f4v*)(Tw + (n * 16 + l15) * 17 + g * 4) = vv;
    }
    asm volatile("s_waitcnt lgkmcnt(0)" ::: "memory");

    // read [c][tok] tile per token, cvt f16, write PO rows: 6 x 1KB bursts
    _Float16* POw = PO + ((size_t)win * 384 + tb) * 192;
    #pragma unroll
    for (int b = 0; b < 6; ++b) {
        int flat = b * 64 + lane;     // 0..383 over 16 tokens x 24 chunks
        int tl = flat / 24;           // token-local 0..15
        int cc = (flat - tl * 24) * 8;
        h8 hv;
        #pragma unroll
        for (int m = 0; m < 8; ++m)
            hv[m] = (_Float16)Tw[(cc + m) * 17 + tl];
        *(h8*)(POw + (size_t)tl * 192 + cc) = hv;
    }
}

// ---------------------------------------------------------------------------
// Kernel 5: writeback — window-reverse + roll-back + transpose to (C,D,H,W).
// Block = one (dd,hh) output row: gather 64 rolled tokens' PO rows (3KB
// contiguous runs) into LDS, then write full 256B (c, 64w) rows.
// ---------------------------------------------------------------------------
__global__ __launch_bounds__(256) void writeback_kernel(
    const _Float16* __restrict__ PO, float* __restrict__ out)
{
    const int bid = blockIdx.x;        // dd*64 + hh
    const int dd = bid >> 6;
    const int hh = bid & 63;
    const int tid = threadIdx.x;

    __shared__ __attribute__((aligned(16))) _Float16 Lw[64 * 196 + 8];

    // inverse roll: window-space coords for this output row
    int d_r = dd + 21; if (d_r >= 24) d_r -= 24;
    int h_r = hh + 60; if (h_r >= 64) h_r -= 64;
    const int wi = d_r / 6, td = d_r - wi * 6;
    const int hi = h_r >> 3, th = h_r & 7;
    const int winbase = (wi * 8 + hi) * 8;
    const int nbase = (td * 8 + th) * 8;

    #pragma unroll
    for (int it = 0; it < 6; ++it) {
        int idx = it * 256 + tid;          // 0..1535 = 64 w x 24 chunks
        int ww = idx / 24;
        int ch = idx - ww * 24;
        int w_r = ww + 60; if (w_r >= 64) w_r -= 64;
        int win = winbase + (w_r >> 3);
        int n = nbase + (w_r & 7);
        h8 v = *(const h8*)(PO + ((size_t)win * 384 + n) * 192 + ch * 8);
        *(h8*)(Lw + ww * 196 + ch * 8) = v;
    }
    __syncthreads();

    float* obase = out + (size_t)dd * 4096 + hh * 64;
    #pragma unroll
    for (int r = 0; r < 3; ++r) {
        const int c = r * 64 + (tid >> 2);
        float* orow = obase + (size_t)c * 98304;
        #pragma unroll
        for (int q = 0; q < 4; ++q) {
            const int w0 = q * 16 + (tid & 3) * 4;   // 4 lanes cover 64B contiguous
            f4v v;
            #pragma unroll
            for (int m = 0; m < 4; ++m)
                v[m] = (float)Lw[(w0 + m) * 196 + c];
            *(f4v*)(orow + w0) = v;
        }
    }
}

// ---------------------------------------------------------------------------
extern "C" void kernel_launch(void* const* d_in, const int* in_sizes, int n_in,
                              void* d_out, int out_size, void* d_ws, size_t ws_size,
                              hipStream_t stream) {
    const float* q_map = (const float*)d_in[0];
    const float* k_map = (const float*)d_in[1];
    const float* v_map = (const float*)d_in[2];
    const float* nqw = (const float*)d_in[3];
    const float* nqb = (const float*)d_in[4];
    const float* nkw = (const float*)d_in[5];
    const float* nkb = (const float*)d_in[6];
    const float* pw = (const float*)d_in[7];
    const float* pb = (const float*)d_in[8];
    float* out = (float*)d_out;

    // workspace layout (f16): Qs, Ks, Vs, AOs each 8*256*384*24 = 18,874,368 elems
    // PO (256*384*192 = same count) ALIASES Qs — Qs is dead after attn_kernel.
    _Float16* ws = (_Float16*)d_ws;
    const size_t BUF = (size_t)8 * 256 * 384 * 24;
    _Float16* Qs = ws;
    _Float16* Ks = ws + BUF;
    _Float16* Vs = ws + 2 * BUF;
    _Float16* AOs = ws + 3 * BUF;
    _Float16* Wb = ws + 4 * BUF;   // + 73728 B, total ~151 MB
    _Float16* PO = Qs;             // alias (safe: sequential stream order)

    ln_stage_kernel<<<dim3(1536, 3), 256, 0, stream>>>(q_map, k_map, v_map,
                                                       nqw, nqb, nkw, nkb, Qs, Ks, Vs);
    wconv_kernel<<<144, 256, 0, stream>>>(pw, Wb);
    attn_kernel<<<dim3(256, 8), 512, 0, stream>>>(Qs, Ks, Vs, AOs);
    proj_kernel<<<1536, 256, 0, stream>>>(AOs, Wb, pb, PO);
    writeback_kernel<<<1536, 256, 0, stream>>>(PO, out);
}

// Round 22
// 208.214 us; speedup vs baseline: 1.0092x; 1.0092x over previous
//
#include <hip/hip_runtime.h>

typedef float f4v __attribute__((ext_vector_type(4)));
typedef _Float16 h8 __attribute__((ext_vector_type(8)));
typedef _Float16 h4 __attribute__((ext_vector_type(4)));
typedef _Float16 h2 __attribute__((ext_vector_type(2)));
typedef __fp16 f16x2 __attribute__((ext_vector_type(2)));

// Problem constants
// C=192, NH=8, DH=24, window 6x8x8 -> N=384 tokens, D/H/W = 24/64/64 -> 256 windows
// shift (3,4,4). Spatial stride per channel = 24*64*64 = 98304.
// Staging layout (f16): [head][win][n][24]  -> slab (head,win) = 384*24 = 9216 elems.
// PO staging (f16): [win][n][192] (aliased onto Qs — dead after attn).

__device__ __forceinline__ float fast_exp2(float x) {
#if __has_builtin(__builtin_amdgcn_exp2f)
    return __builtin_amdgcn_exp2f(x);
#else
    return exp2f(x);
#endif
}
__device__ __forceinline__ float fast_rcp(float x) {
#if __has_builtin(__builtin_amdgcn_rcpf)
    return __builtin_amdgcn_rcpf(x);
#else
    return 1.0f / x;
#endif
}

// region slot for token n (3-bit: d,h,w boundary crossing), block-uniform wi/hi/wj
__device__ __forceinline__ int region_slot(int n, int wi, int hi, int wj) {
    int s = 0;
    if (wi == 3 && (n >> 6) >= 3) s += 4;
    if (hi == 7 && ((n >> 3) & 7) >= 4) s += 2;
    if (wj == 7 && (n & 7) >= 4) s += 1;
    return s;
}

// ---------------------------------------------------------------------------
// Kernel 1: transpose + roll + window-partition + LayerNorm -> f16 staging.
// r22: GRANULE fix. Occupancy (r18/r21), MLP (r20), conflicts (r21) all
// exonerated — ln is DRAM-granule bound (256B reads -> 2.2TB/s; writeback's
// ~3KB runs -> ~5TB/s; streaming -> 6.3). Block now covers 2 ADJACENT h-rows:
// each c-row load is one contiguous 512B run (2x granule). 128 tokens/block,
// grid (768,3). Tile [192][132] f16 (~50.7KB, stride 264B -> 2-way banks);
// per-wave shfl_xor(32) partials -> [4][128]. LDS ~56KB -> 2 blocks/CU
// (occupancy proven non-binding for this kernel).
// ---------------------------------------------------------------------------
__global__ __launch_bounds__(256) void ln_stage_kernel(
    const float* __restrict__ q, const float* __restrict__ k, const float* __restrict__ v,
    const float* __restrict__ nqw, const float* __restrict__ nqb,
    const float* __restrict__ nkw, const float* __restrict__ nkb,
    _Float16* __restrict__ Qs, _Float16* __restrict__ Ks, _Float16* __restrict__ Vs)
{
    const int tid = threadIdx.x;
    const int bid = blockIdx.x;      // d*32 + h2
    const int tensor = blockIdx.y;   // 0=q, 1=k, 2=v
    const int d = bid >> 5;
    const int h2 = bid & 31;         // h = 2*h2 + h_loc

    const float* src = (tensor == 0) ? q : (tensor == 1) ? k : v;
    const float* gam = (tensor == 0) ? nqw : nkw;
    const float* bet = (tensor == 0) ? nqb : nkb;
    _Float16* dst = (tensor == 0) ? Qs : (tensor == 1) ? Ks : Vs;
    // fold softmax scale (1/sqrt(24)) and log2(e) into Q so scores are in exp2 domain
    const float scale = (tensor == 0) ? (0.20412414523193154f * 1.44269504088896340f) : 1.0f;

    __shared__ __attribute__((aligned(16))) _Float16 tile[192][132]; // [c][token pad132]
    __shared__ __attribute__((aligned(16))) float psum4[4][128];
    __shared__ __attribute__((aligned(16))) float psq4[4][128];
    __shared__ float smean[128];
    __shared__ float srstd[128];
    __shared__ float sgam[192];
    __shared__ float sbet[192];

    if (tid < 192) { sgam[tid] = gam[tid]; sbet[tid] = bet[tid]; }

    const int lane = tid & 63;
    const int wid = tid >> 6;
    const int cg = tid >> 5;           // 0..7 channel-group
    const int fp = tid & 31;           // f4v slot within the 512B row (f = fp*4)

    // phase 1: 24 contiguous 512B-row loads (c = r*8 + cg) + partials + f16 tile
    {
        const float* base = src + (size_t)d * 4096 + (size_t)(h2 * 2) * 64 + fp * 4;
        f4v s4 = {}, ss4 = {};
        #pragma unroll
        for (int r = 0; r < 24; ++r) {
            const int c = r * 8 + cg;
            f4v x = *(const f4v*)(base + (size_t)c * 98304);
            s4 += x;
            ss4 += x * x;
            h4 hx;
            hx[0] = (_Float16)x[0]; hx[1] = (_Float16)x[1];
            hx[2] = (_Float16)x[2]; hx[3] = (_Float16)x[3];
            *(h4*)&tile[c][fp * 4] = hx;
        }
        // merge the two c-groups within each wave (lanes 0-31 vs 32-63)
        #pragma unroll
        for (int m = 0; m < 4; ++m) {
            s4[m] += __shfl_xor(s4[m], 32);
            ss4[m] += __shfl_xor(ss4[m], 32);
        }
        if (lane < 32) {
            *(f4v*)&psum4[wid][lane * 4] = s4;
            *(f4v*)&psq4[wid][lane * 4] = ss4;
        }
    }
    __syncthreads();

    // phase 2: combine 4 per-wave partials per token (128 tokens)
    if (tid < 128) {
        float S = psum4[0][tid] + psum4[1][tid] + psum4[2][tid] + psum4[3][tid];
        float SS = psq4[0][tid] + psq4[1][tid] + psq4[2][tid] + psq4[3][tid];
        float mean = S * (1.0f / 192.0f);
        float var = SS * (1.0f / 192.0f) - mean * mean;
        smean[tid] = mean;
        srstd[tid] = rsqrtf(var + 1e-5f);
    }
    __syncthreads();

    // phase 3: normalize + write f16 staging, head-major: [head][win][n][24]
    // 2 threads per token: p = tid>>7 selects heads 4p..4p+3 (96 channels)
    {
        const int t = tid & 127;     // token: h_loc*64 + w
        const int p = tid >> 7;
        const float mean = smean[t];
        const float rstd = srstd[t];
        const int h = h2 * 2 + (t >> 6);
        const int w = t & 63;
        int d_r = d + 21; if (d_r >= 24) d_r -= 24;
        int h_r = h + 60; if (h_r >= 64) h_r -= 64;
        int w_r = w + 60; if (w_r >= 64) w_r -= 64;
        const int wi = d_r / 6, td = d_r - wi * 6;
        const int hi = h_r >> 3, th = h_r & 7;
        const int wj = w_r >> 3, tw = w_r & 7;
        const int win = (wi * 8 + hi) * 8 + wj;
        const int n = (td * 8 + th) * 8 + tw;
        #pragma unroll
        for (int hh2 = 0; hh2 < 4; ++hh2) {
            const int head = p * 4 + hh2;
            _Float16* outp = dst + (size_t)(head * 256 + win) * 9216 + n * 24;
            #pragma unroll
            for (int cc = 0; cc < 3; ++cc) {
                const int c = head * 24 + cc * 8;
                h8 hv;
                #pragma unroll
                for (int j = 0; j < 8; ++j) {
                    float x = ((float)tile[c + j][t] - mean) * rstd * sgam[c + j] + sbet[c + j];
                    hv[j] = (_Float16)(x * scale);
                }
                *(h8*)(outp + cc * 8) = hv;
            }
        }
    }
}

// ---------------------------------------------------------------------------
// Kernel 2: proj_w f32 -> f16
// ---------------------------------------------------------------------------
__global__ __launch_bounds__(256) void wconv_kernel(const float* __restrict__ w,
                                                    _Float16* __restrict__ wb)
{
    int i = blockIdx.x * 256 + threadIdx.x;
    if (i < 192 * 192) wb[i] = (_Float16)w[i];
}

// ---------------------------------------------------------------------------
// attn epilogue: rowsum comes FREE from o1's duplicate lanes (l15>=8 read the
// ones-row) -> inv via one shfl per j. Wave-private Ob sub-tile; per-wave DS
// ordering + lgkmcnt fence (proven r4+).
// ---------------------------------------------------------------------------
__device__ __forceinline__ void attn_epilogue(
    f4v o0, f4v o1, _Float16* __restrict__ Op,
    _Float16* __restrict__ AOw, int q0, int lane, int l15, int g)
{
    #pragma unroll
    for (int j = 0; j < 4; ++j) {
        float rs = __shfl(o1[j], (g << 4) | 8);   // lane l15=8 of this g holds rowsum
        float inv = fast_rcp(rs);
        const int r = 4 * g + j;
        Op[r * 24 + l15] = (_Float16)(o0[j] * inv);
        if (l15 < 8) Op[r * 24 + 16 + l15] = (_Float16)(o1[j] * inv);
    }
    asm volatile("s_waitcnt lgkmcnt(0)" ::: "memory");
    // coalesced 768B burst: 48 lanes x 16B contiguous
    if (lane < 48) {
        h8 ov = *(const h8*)(Op + lane * 8);
        *(h8*)(AOw + (size_t)q0 * 24 + lane * 8) = ov;
    }
    asm volatile("" ::: "memory");
}

// ---------------------------------------------------------------------------
// Kernel 3: windowed attention, one block per (window, head). 8 WAVES (512t).
// r17 structure (unchanged): region-channel masking in the K=32 pad (one-hot
// * sqrt(40), cinit -46 -> masked p == 0 in f16); rowsum via ones-row in o1's
// duplicate lanes; 2+1 split fusion (pass A fuses qt{0,1}, pass B = qt2,
// pass-A AO stores hide under pass B). VGPR ~124 at (512,2) — do not perturb.
// ---------------------------------------------------------------------------
__global__ __launch_bounds__(512, 2) void attn_kernel(
    const _Float16* __restrict__ Qs, const _Float16* __restrict__ Ks,
    const _Float16* __restrict__ Vs, _Float16* __restrict__ AOs)
{
    const int win = blockIdx.x;
    const int head = blockIdx.y;
    const int tid = threadIdx.x;
    const int lane = tid & 63;
    const int wid = tid >> 6;        // 0..7
    const int l15 = lane & 15;
    const int g = lane >> 4;

    __shared__ __attribute__((aligned(16))) _Float16 Kh[384 * 36];      // [token][36]: dh0..23, onehot 24..31, pad
    __shared__ __attribute__((aligned(16))) _Float16 Vt[25 * 388];      // [dh][token pad388]; row 24 = ones
    __shared__ __attribute__((aligned(16))) _Float16 Ob[8][2][16 * 24]; // per-wave, qt-parity dbuf

    const int wi = win >> 6, hi = (win >> 3) & 7, wj = win & 7;

    const size_t slab = (size_t)(head * 256 + win) * 9216;
    const _Float16* Kw = Ks + slab;
    const _Float16* Vw = Vs + slab;
    const _Float16* Qw = Qs + slab;
    _Float16* AOw = AOs + slab;

    const _Float16 mreg = (_Float16)6.32455532f;   // sqrt(40)

    // ---- hoist this wave's 3 Q fragments; g==3 = one-hot(region(q)) * m ----
    h8 qreg[3];
    #pragma unroll
    for (int qt = 0; qt < 3; ++qt) {
        h8 z = {};
        if (g < 3) {
            z = *(const h8*)(Qw + (size_t)(wid * 48 + qt * 16 + l15) * 24 + g * 8);
        } else {
            int slot = region_slot(wid * 48 + qt * 16 + l15, wi, hi, wj);
            #pragma unroll
            for (int j = 0; j < 8; ++j) z[j] = (slot == j) ? mreg : (_Float16)0.f;
        }
        qreg[qt] = z;
    }

    // ---- stage K (36-wide rows + one-hot tails), V^T, ones-row ----
    {
        const h8* K8 = (const h8*)Kw;
        const h8* V8 = (const h8*)Vw;
        #pragma unroll
        for (int it = 0; it < 5; ++it) {
            int idx = it * 512 + tid;        // 0..2303 ; 0..1151 = K, 1152.. = V
            if (idx < 1152) {
                int n = idx / 3;
                int ch = idx - n * 3;
                *(h8*)(Kh + n * 36 + ch * 8) = K8[idx];
            } else if (idx < 2304) {
                int i = idx - 1152;          // flat h8 index in V slab
                int n = i / 3;               // token
                int ch = i - n * 3;          // 8-dh chunk
                h8 vv = V8[i];
                #pragma unroll
                for (int j = 0; j < 8; ++j) Vt[(ch * 8 + j) * 388 + n] = vv[j];
            }
        }
        if (tid < 384) {
            int slot = region_slot(tid, wi, hi, wj);
            h8 t;
            #pragma unroll
            for (int j = 0; j < 8; ++j) t[j] = (slot == j) ? mreg : (_Float16)0.f;
            *(h8*)(Kh + tid * 36 + 24) = t;
            Vt[24 * 388 + tid] = (_Float16)1.f;   // ones-row for rowsum
        }
    }
    __syncthreads();

    // lanes 0-7 of o1 -> dh 16-23; lanes 8-15 -> ones row (rowsum)
    const int v1row = (l15 < 8) ? (16 + l15) : 24;
    const int q0w = wid * 48;

    // ---- PASS A: fused qt0+qt1 mt loop (shared kf/v0/v1; 2 chains) ----
    f4v o0_0 = {}, o1_0 = {}, o0_1 = {}, o1_1 = {};
    #pragma unroll
    for (int mt = 0; mt < 24; ++mt) {
        h8 kf = *(const h8*)(Kh + (16 * mt + l15) * 36 + g * 8);
        h4 v0 = *(const h4*)(Vt + l15 * 388 + 16 * mt + 4 * g);
        h4 v1 = *(const h4*)(Vt + v1row * 388 + 16 * mt + 4 * g);
        const f4v cinit = {-46.f, -46.f, -46.f, -46.f};

        // qt0 chain
        {
            f4v s4 = __builtin_amdgcn_mfma_f32_16x16x32_f16(kf, qreg[0], cinit, 0, 0, 0);
            float p0 = fast_exp2(s4[0]), p1 = fast_exp2(s4[1]);
            float p2 = fast_exp2(s4[2]), p3 = fast_exp2(s4[3]);
            union { f16x2 gp[2]; h4 v; } pu;
            pu.gp[0] = __builtin_amdgcn_cvt_pkrtz(p0, p1);
            pu.gp[1] = __builtin_amdgcn_cvt_pkrtz(p2, p3);
            o0_0 = __builtin_amdgcn_mfma_f32_16x16x16f16(pu.v, v0, o0_0, 0, 0, 0);
            o1_0 = __builtin_amdgcn_mfma_f32_16x16x16f16(pu.v, v1, o1_0, 0, 0, 0);
        }
        // qt1 chain
        {
            f4v s4 = __builtin_amdgcn_mfma_f32_16x16x32_f16(kf, qreg[1], cinit, 0, 0, 0);
            float p0 = fast_exp2(s4[0]), p1 = fast_exp2(s4[1]);
            float p2 = fast_exp2(s4[2]), p3 = fast_exp2(s4[3]);
            union { f16x2 gp[2]; h4 v; } pu;
            pu.gp[0] = __builtin_amdgcn_cvt_pkrtz(p0, p1);
            pu.gp[1] = __builtin_amdgcn_cvt_pkrtz(p2, p3);
            o0_1 = __builtin_amdgcn_mfma_f32_16x16x16f16(pu.v, v0, o0_1, 0, 0, 0);
            o1_1 = __builtin_amdgcn_mfma_f32_16x16x16f16(pu.v, v1, o1_1, 0, 0, 0);
        }
    }

    // pass-A epilogues (AO stores issue now; latency hides under pass B)
    attn_epilogue(o0_0, o1_0, Ob[wid][0], AOw, q0w,      lane, l15, g);
    attn_epilogue(o0_1, o1_1, Ob[wid][1], AOw, q0w + 16, lane, l15, g);

    // ---- PASS B: qt2 alone (a/b acc split for dep-breaking) ----
    f4v o0a = {}, o0b = {}, o1a = {}, o1b = {};
    #pragma unroll
    for (int mt = 0; mt < 24; ++mt) {
        h8 kf = *(const h8*)(Kh + (16 * mt + l15) * 36 + g * 8);
        h4 v0 = *(const h4*)(Vt + l15 * 388 + 16 * mt + 4 * g);
        h4 v1 = *(const h4*)(Vt + v1row * 388 + 16 * mt + 4 * g);
        const f4v cinit = {-46.f, -46.f, -46.f, -46.f};
        f4v s4 = __builtin_amdgcn_mfma_f32_16x16x32_f16(kf, qreg[2], cinit, 0, 0, 0);
        float p0 = fast_exp2(s4[0]), p1 = fast_exp2(s4[1]);
        float p2 = fast_exp2(s4[2]), p3 = fast_exp2(s4[3]);
        union { f16x2 gp[2]; h4 v; } pu;
        pu.gp[0] = __builtin_amdgcn_cvt_pkrtz(p0, p1);
        pu.gp[1] = __builtin_amdgcn_cvt_pkrtz(p2, p3);
        if (mt & 1) {
            o0b = __builtin_amdgcn_mfma_f32_16x16x16f16(pu.v, v0, o0b, 0, 0, 0);
            o1b = __builtin_amdgcn_mfma_f32_16x16x16f16(pu.v, v1, o1b, 0, 0, 0);
        } else {
            o0a = __builtin_amdgcn_mfma_f32_16x16x16f16(pu.v, v0, o0a, 0, 0, 0);
            o1a = __builtin_amdgcn_mfma_f32_16x16x16f16(pu.v, v1, o1a, 0, 0, 0);
        }
    }
    attn_epilogue(o0a + o0b, o1a + o1b, Ob[wid][0], AOw, q0w + 32, lane, l15, g);
}

// ---------------------------------------------------------------------------
// Kernel 4: projection (X @ W^T + b) -> PO staging [win][n][192] f16.
// Each wave's 16-token tile = 6KB contiguous PO region written as 1KB/instr
// h8 bursts -> full-line HBM writes.
// ---------------------------------------------------------------------------
__global__ __launch_bounds__(256) void proj_kernel(
    const _Float16* __restrict__ AOs, const _Float16* __restrict__ Wb,
    const float* __restrict__ bias, _Float16* __restrict__ PO)
{
    const int bid = blockIdx.x;             // 0..1535
    const int win = bid / 6;
    const int r6 = bid - win * 6;
    const int half = r6 / 3;
    const int mi = r6 - half * 3;
    const int tid = threadIdx.x;
    const int lane = tid & 63, wid = tid >> 6;
    const int l15 = lane & 15, g = lane >> 4;

    __shared__ __attribute__((aligned(16))) float tileT[4][192 * 17];
    float* Tw = tileT[wid];

    const int tb = half * 192 + mi * 64 + wid * 16;

    // per-lane fragment -> (head, sub-chunk) decomposition for m = kk*4+g
    int hdk[6], sbk[6];
    #pragma unroll
    for (int kk = 0; kk < 6; ++kk) {
        int mm = kk * 4 + g;
        hdk[kk] = mm / 3;
        sbk[kk] = mm - 3 * hdk[kk];
    }

    // preload this wave's 6 A-fragments (16 tokens x 32 channels each)
    h8 af[6];
    #pragma unroll
    for (int kk = 0; kk < 6; ++kk)
        af[kk] = *(const h8*)(AOs + (size_t)(hdk[kk] * 256 + win) * 9216
                                  + (size_t)(tb + l15) * 24 + sbk[kk] * 8);

    // GEMM: n-outer, kk-inner (bounds live bf fragments; acc[n] hot)
    f4v acc[12];
    #pragma unroll
    for (int n = 0; n < 12; ++n) {
        f4v a = {};
        #pragma unroll
        for (int kk = 0; kk < 6; ++kk) {
            h8 bf = *(const h8*)(Wb + (size_t)(n * 16 + l15) * 192 + kk * 32 + g * 8);
            a = __builtin_amdgcn_mfma_f32_16x16x32_f16(af[kk], bf, a, 0, 0, 0);
        }
        acc[n] = a;
    }

    // bias + transpose through wave-private LDS ([c][token16] pad17)
    #pragma unroll
    for (int n = 0; n < 12; ++n) {
        float b = bias[n * 16 + l15];
        f4v vv = acc[n];
        vv[0] += b; vv[1] += b; vv[2] += b; vv[3] += b;
        *(f4v*)(Tw + (n * 16 + l15) * 17 + g * 4) = vv;
    }
    asm volatile("s_waitcnt lgkmcnt(0)" ::: "memory");

    // read [c][tok] tile per token, cvt f16, write PO rows: 6 x 1KB bursts
    _Float16* POw = PO + ((size_t)win * 384 + tb) * 192;
    #pragma unroll
    for (int b = 0; b < 6; ++b) {
        int flat = b * 64 + lane;     // 0..383 over 16 tokens x 24 chunks
        int tl = flat / 24;           // token-local 0..15
        int cc = (flat - tl * 24) * 8;
        h8 hv;
        #pragma unroll
        for (int m = 0; m < 8; ++m)
            hv[m] = (_Float16)Tw[(cc + m) * 17 + tl];
        *(h8*)(POw + (size_t)tl * 192 + cc) = hv;
    }
}

// ---------------------------------------------------------------------------
// Kernel 5: writeback — window-reverse + roll-back + transpose to (C,D,H,W).
// Block = one (dd,hh) output row: gather 64 rolled tokens' PO rows (3KB
// contiguous runs) into LDS, then write full 256B (c, 64w) rows.
// ---------------------------------------------------------------------------
__global__ __launch_bounds__(256) void writeback_kernel(
    const _Float16* __restrict__ PO, float* __restrict__ out)
{
    const int bid = blockIdx.x;        // dd*64 + hh
    const int dd = bid >> 6;
    const int hh = bid & 63;
    const int tid = threadIdx.x;

    __shared__ __attribute__((aligned(16))) _Float16 Lw[64 * 196 + 8];

    // inverse roll: window-space coords for this output row
    int d_r = dd + 21; if (d_r >= 24) d_r -= 24;
    int h_r = hh + 60; if (h_r >= 64) h_r -= 64;
    const int wi = d_r / 6, td = d_r - wi * 6;
    const int hi = h_r >> 3, th = h_r & 7;
    const int winbase = (wi * 8 + hi) * 8;
    const int nbase = (td * 8 + th) * 8;

    #pragma unroll
    for (int it = 0; it < 6; ++it) {
        int idx = it * 256 + tid;          // 0..1535 = 64 w x 24 chunks
        int ww = idx / 24;
        int ch = idx - ww * 24;
        int w_r = ww + 60; if (w_r >= 64) w_r -= 64;
        int win = winbase + (w_r >> 3);
        int n = nbase + (w_r & 7);
        h8 v = *(const h8*)(PO + ((size_t)win * 384 + n) * 192 + ch * 8);
        *(h8*)(Lw + ww * 196 + ch * 8) = v;
    }
    __syncthreads();

    float* obase = out + (size_t)dd * 4096 + hh * 64;
    #pragma unroll
    for (int r = 0; r < 3; ++r) {
        const int c = r * 64 + (tid >> 2);
        float* orow = obase + (size_t)c * 98304;
        #pragma unroll
        for (int q = 0; q < 4; ++q) {
            const int w0 = q * 16 + (tid & 3) * 4;   // 4 lanes cover 64B contiguous
            f4v v;
            #pragma unroll
            for (int m = 0; m < 4; ++m)
                v[m] = (float)Lw[(w0 + m) * 196 + c];
            *(f4v*)(orow + w0) = v;
        }
    }
}

// ---------------------------------------------------------------------------
extern "C" void kernel_launch(void* const* d_in, const int* in_sizes, int n_in,
                              void* d_out, int out_size, void* d_ws, size_t ws_size,
                              hipStream_t stream) {
    const float* q_map = (const float*)d_in[0];
    const float* k_map = (const float*)d_in[1];
    const float* v_map = (const float*)d_in[2];
    const float* nqw = (const float*)d_in[3];
    const float* nqb = (const float*)d_in[4];
    const float* nkw = (const float*)d_in[5];
    const float* nkb = (const float*)d_in[6];
    const float* pw = (const float*)d_in[7];
    const float* pb = (const float*)d_in[8];
    float* out = (float*)d_out;

    // workspace layout (f16): Qs, Ks, Vs, AOs each 8*256*384*24 = 18,874,368 elems
    // PO (256*384*192 = same count) ALIASES Qs — Qs is dead after attn_kernel.
    _Float16* ws = (_Float16*)d_ws;
    const size_t BUF = (size_t)8 * 256 * 384 * 24;
    _Float16* Qs = ws;
    _Float16* Ks = ws + BUF;
    _Float16* Vs = ws + 2 * BUF;
    _Float16* AOs = ws + 3 * BUF;
    _Float16* Wb = ws + 4 * BUF;   // + 73728 B, total ~151 MB
    _Float16* PO = Qs;             // alias (safe: sequential stream order)

    ln_stage_kernel<<<dim3(768, 3), 256, 0, stream>>>(q_map, k_map, v_map,
                                                      nqw, nqb, nkw, nkb, Qs, Ks, Vs);
    wconv_kernel<<<144, 256, 0, stream>>>(pw, Wb);
    attn_kernel<<<dim3(256, 8), 512, 0, stream>>>(Qs, Ks, Vs, AOs);
    proj_kernel<<<1536, 256, 0, stream>>>(AOs, Wb, pb, PO);
    writeback_kernel<<<1536, 256, 0, stream>>>(PO, out);
}

// Round 23
// 194.530 us; speedup vs baseline: 1.0801x; 1.0703x over previous
//
#include <hip/hip_runtime.h>

typedef float f4v __attribute__((ext_vector_type(4)));
typedef _Float16 h8 __attribute__((ext_vector_type(8)));
typedef _Float16 h4 __attribute__((ext_vector_type(4)));
typedef _Float16 h2 __attribute__((ext_vector_type(2)));
typedef __fp16 f16x2 __attribute__((ext_vector_type(2)));

// Problem constants
// C=192, NH=8, DH=24, window 6x8x8 -> N=384 tokens, D/H/W = 24/64/64 -> 256 windows
// shift (3,4,4). Spatial stride per channel = 24*64*64 = 98304.
// Staging layout (f16): [head][win][n][24]  -> slab (head,win) = 384*24 = 9216 elems.

__device__ __forceinline__ float fast_exp2(float x) {
#if __has_builtin(__builtin_amdgcn_exp2f)
    return __builtin_amdgcn_exp2f(x);
#else
    return exp2f(x);
#endif
}
__device__ __forceinline__ float fast_rcp(float x) {
#if __has_builtin(__builtin_amdgcn_rcpf)
    return __builtin_amdgcn_rcpf(x);
#else
    return 1.0f / x;
#endif
}

// region slot for token n (3-bit: d,h,w boundary crossing), block-uniform wi/hi/wj
__device__ __forceinline__ int region_slot(int n, int wi, int hi, int wj) {
    int s = 0;
    if (wi == 3 && (n >> 6) >= 3) s += 4;
    if (hi == 7 && ((n >> 3) & 7) >= 4) s += 2;
    if (wj == 7 && (n & 7) >= 4) s += 1;
    return s;
}

// ---------------------------------------------------------------------------
// Kernel 1: transpose + roll + window-partition + LayerNorm -> f16 staging.
// r22 form, declared STRUCTURAL: at the mixed R+W HBM-stream cap (~2.2TB/s
// HBM, 3.3TB/s logical). Occupancy (r18/r21), MLP (r19/r20), bank conflicts
// (r21, now 0), and DRAM granule (r22) all falsified as levers — do not touch.
// ---------------------------------------------------------------------------
__global__ __launch_bounds__(256) void ln_stage_kernel(
    const float* __restrict__ q, const float* __restrict__ k, const float* __restrict__ v,
    const float* __restrict__ nqw, const float* __restrict__ nqb,
    const float* __restrict__ nkw, const float* __restrict__ nkb,
    _Float16* __restrict__ Qs, _Float16* __restrict__ Ks, _Float16* __restrict__ Vs)
{
    const int tid = threadIdx.x;
    const int bid = blockIdx.x;      // d*32 + h2
    const int tensor = blockIdx.y;   // 0=q, 1=k, 2=v
    const int d = bid >> 5;
    const int h2 = bid & 31;         // h = 2*h2 + h_loc

    const float* src = (tensor == 0) ? q : (tensor == 1) ? k : v;
    const float* gam = (tensor == 0) ? nqw : nkw;
    const float* bet = (tensor == 0) ? nqb : nkb;
    _Float16* dst = (tensor == 0) ? Qs : (tensor == 1) ? Ks : Vs;
    // fold softmax scale (1/sqrt(24)) and log2(e) into Q so scores are in exp2 domain
    const float scale = (tensor == 0) ? (0.20412414523193154f * 1.44269504088896340f) : 1.0f;

    __shared__ __attribute__((aligned(16))) _Float16 tile[192][132]; // [c][token pad132]
    __shared__ __attribute__((aligned(16))) float psum4[4][128];
    __shared__ __attribute__((aligned(16))) float psq4[4][128];
    __shared__ float smean[128];
    __shared__ float srstd[128];
    __shared__ float sgam[192];
    __shared__ float sbet[192];

    if (tid < 192) { sgam[tid] = gam[tid]; sbet[tid] = bet[tid]; }

    const int lane = tid & 63;
    const int wid = tid >> 6;
    const int cg = tid >> 5;           // 0..7 channel-group
    const int fp = tid & 31;           // f4v slot within the 512B row (f = fp*4)

    // phase 1: 24 contiguous 512B-row loads (c = r*8 + cg) + partials + f16 tile
    {
        const float* base = src + (size_t)d * 4096 + (size_t)(h2 * 2) * 64 + fp * 4;
        f4v s4 = {}, ss4 = {};
        #pragma unroll
        for (int r = 0; r < 24; ++r) {
            const int c = r * 8 + cg;
            f4v x = *(const f4v*)(base + (size_t)c * 98304);
            s4 += x;
            ss4 += x * x;
            h4 hx;
            hx[0] = (_Float16)x[0]; hx[1] = (_Float16)x[1];
            hx[2] = (_Float16)x[2]; hx[3] = (_Float16)x[3];
            *(h4*)&tile[c][fp * 4] = hx;
        }
        // merge the two c-groups within each wave (lanes 0-31 vs 32-63)
        #pragma unroll
        for (int m = 0; m < 4; ++m) {
            s4[m] += __shfl_xor(s4[m], 32);
            ss4[m] += __shfl_xor(ss4[m], 32);
        }
        if (lane < 32) {
            *(f4v*)&psum4[wid][lane * 4] = s4;
            *(f4v*)&psq4[wid][lane * 4] = ss4;
        }
    }
    __syncthreads();

    // phase 2: combine 4 per-wave partials per token (128 tokens)
    if (tid < 128) {
        float S = psum4[0][tid] + psum4[1][tid] + psum4[2][tid] + psum4[3][tid];
        float SS = psq4[0][tid] + psq4[1][tid] + psq4[2][tid] + psq4[3][tid];
        float mean = S * (1.0f / 192.0f);
        float var = SS * (1.0f / 192.0f) - mean * mean;
        smean[tid] = mean;
        srstd[tid] = rsqrtf(var + 1e-5f);
    }
    __syncthreads();

    // phase 3: normalize + write f16 staging, head-major: [head][win][n][24]
    // 2 threads per token: p = tid>>7 selects heads 4p..4p+3 (96 channels)
    {
        const int t = tid & 127;     // token: h_loc*64 + w
        const int p = tid >> 7;
        const float mean = smean[t];
        const float rstd = srstd[t];
        const int h = h2 * 2 + (t >> 6);
        const int w = t & 63;
        int d_r = d + 21; if (d_r >= 24) d_r -= 24;
        int h_r = h + 60; if (h_r >= 64) h_r -= 64;
        int w_r = w + 60; if (w_r >= 64) w_r -= 64;
        const int wi = d_r / 6, td = d_r - wi * 6;
        const int hi = h_r >> 3, th = h_r & 7;
        const int wj = w_r >> 3, tw = w_r & 7;
        const int win = (wi * 8 + hi) * 8 + wj;
        const int n = (td * 8 + th) * 8 + tw;
        #pragma unroll
        for (int hh2 = 0; hh2 < 4; ++hh2) {
            const int head = p * 4 + hh2;
            _Float16* outp = dst + (size_t)(head * 256 + win) * 9216 + n * 24;
            #pragma unroll
            for (int cc = 0; cc < 3; ++cc) {
                const int c = head * 24 + cc * 8;
                h8 hv;
                #pragma unroll
                for (int j = 0; j < 8; ++j) {
                    float x = ((float)tile[c + j][t] - mean) * rstd * sgam[c + j] + sbet[c + j];
                    hv[j] = (_Float16)(x * scale);
                }
                *(h8*)(outp + cc * 8) = hv;
            }
        }
    }
}

// ---------------------------------------------------------------------------
// Kernel 2: proj_w f32 -> f16
// ---------------------------------------------------------------------------
__global__ __launch_bounds__(256) void wconv_kernel(const float* __restrict__ w,
                                                    _Float16* __restrict__ wb)
{
    int i = blockIdx.x * 256 + threadIdx.x;
    if (i < 192 * 192) wb[i] = (_Float16)w[i];
}

// ---------------------------------------------------------------------------
// attn epilogue: rowsum comes FREE from o1's duplicate lanes (l15>=8 read the
// ones-row) -> inv via one shfl per j. Wave-private Ob sub-tile; per-wave DS
// ordering + lgkmcnt fence (proven r4+).
// ---------------------------------------------------------------------------
__device__ __forceinline__ void attn_epilogue(
    f4v o0, f4v o1, _Float16* __restrict__ Op,
    _Float16* __restrict__ AOw, int q0, int lane, int l15, int g)
{
    #pragma unroll
    for (int j = 0; j < 4; ++j) {
        float rs = __shfl(o1[j], (g << 4) | 8);   // lane l15=8 of this g holds rowsum
        float inv = fast_rcp(rs);
        const int r = 4 * g + j;
        Op[r * 24 + l15] = (_Float16)(o0[j] * inv);
        if (l15 < 8) Op[r * 24 + 16 + l15] = (_Float16)(o1[j] * inv);
    }
    asm volatile("s_waitcnt lgkmcnt(0)" ::: "memory");
    // coalesced 768B burst: 48 lanes x 16B contiguous
    if (lane < 48) {
        h8 ov = *(const h8*)(Op + lane * 8);
        *(h8*)(AOw + (size_t)q0 * 24 + lane * 8) = ov;
    }
    asm volatile("" ::: "memory");
}

// ---------------------------------------------------------------------------
// Kernel 3: windowed attention, one block per (window, head). 8 WAVES (512t).
// r17 structure (unchanged): region-channel masking in the K=32 pad (one-hot
// * sqrt(40), cinit -46 -> masked p == 0 in f16); rowsum via ones-row in o1's
// duplicate lanes; 2+1 split fusion (pass A fuses qt{0,1}, pass B = qt2,
// pass-A AO stores hide under pass B). VGPR ~124 at (512,2) — do not perturb.
// ---------------------------------------------------------------------------
__global__ __launch_bounds__(512, 2) void attn_kernel(
    const _Float16* __restrict__ Qs, const _Float16* __restrict__ Ks,
    const _Float16* __restrict__ Vs, _Float16* __restrict__ AOs)
{
    const int win = blockIdx.x;
    const int head = blockIdx.y;
    const int tid = threadIdx.x;
    const int lane = tid & 63;
    const int wid = tid >> 6;        // 0..7
    const int l15 = lane & 15;
    const int g = lane >> 4;

    __shared__ __attribute__((aligned(16))) _Float16 Kh[384 * 36];      // [token][36]: dh0..23, onehot 24..31, pad
    __shared__ __attribute__((aligned(16))) _Float16 Vt[25 * 388];      // [dh][token pad388]; row 24 = ones
    __shared__ __attribute__((aligned(16))) _Float16 Ob[8][2][16 * 24]; // per-wave, qt-parity dbuf

    const int wi = win >> 6, hi = (win >> 3) & 7, wj = win & 7;

    const size_t slab = (size_t)(head * 256 + win) * 9216;
    const _Float16* Kw = Ks + slab;
    const _Float16* Vw = Vs + slab;
    const _Float16* Qw = Qs + slab;
    _Float16* AOw = AOs + slab;

    const _Float16 mreg = (_Float16)6.32455532f;   // sqrt(40)

    // ---- hoist this wave's 3 Q fragments; g==3 = one-hot(region(q)) * m ----
    h8 qreg[3];
    #pragma unroll
    for (int qt = 0; qt < 3; ++qt) {
        h8 z = {};
        if (g < 3) {
            z = *(const h8*)(Qw + (size_t)(wid * 48 + qt * 16 + l15) * 24 + g * 8);
        } else {
            int slot = region_slot(wid * 48 + qt * 16 + l15, wi, hi, wj);
            #pragma unroll
            for (int j = 0; j < 8; ++j) z[j] = (slot == j) ? mreg : (_Float16)0.f;
        }
        qreg[qt] = z;
    }

    // ---- stage K (36-wide rows + one-hot tails), V^T, ones-row ----
    {
        const h8* K8 = (const h8*)Kw;
        const h8* V8 = (const h8*)Vw;
        #pragma unroll
        for (int it = 0; it < 5; ++it) {
            int idx = it * 512 + tid;        // 0..2303 ; 0..1151 = K, 1152.. = V
            if (idx < 1152) {
                int n = idx / 3;
                int ch = idx - n * 3;
                *(h8*)(Kh + n * 36 + ch * 8) = K8[idx];
            } else if (idx < 2304) {
                int i = idx - 1152;          // flat h8 index in V slab
                int n = i / 3;               // token
                int ch = i - n * 3;          // 8-dh chunk
                h8 vv = V8[i];
                #pragma unroll
                for (int j = 0; j < 8; ++j) Vt[(ch * 8 + j) * 388 + n] = vv[j];
            }
        }
        if (tid < 384) {
            int slot = region_slot(tid, wi, hi, wj);
            h8 t;
            #pragma unroll
            for (int j = 0; j < 8; ++j) t[j] = (slot == j) ? mreg : (_Float16)0.f;
            *(h8*)(Kh + tid * 36 + 24) = t;
            Vt[24 * 388 + tid] = (_Float16)1.f;   // ones-row for rowsum
        }
    }
    __syncthreads();

    // lanes 0-7 of o1 -> dh 16-23; lanes 8-15 -> ones row (rowsum)
    const int v1row = (l15 < 8) ? (16 + l15) : 24;
    const int q0w = wid * 48;

    // ---- PASS A: fused qt0+qt1 mt loop (shared kf/v0/v1; 2 chains) ----
    f4v o0_0 = {}, o1_0 = {}, o0_1 = {}, o1_1 = {};
    #pragma unroll
    for (int mt = 0; mt < 24; ++mt) {
        h8 kf = *(const h8*)(Kh + (16 * mt + l15) * 36 + g * 8);
        h4 v0 = *(const h4*)(Vt + l15 * 388 + 16 * mt + 4 * g);
        h4 v1 = *(const h4*)(Vt + v1row * 388 + 16 * mt + 4 * g);
        const f4v cinit = {-46.f, -46.f, -46.f, -46.f};

        // qt0 chain
        {
            f4v s4 = __builtin_amdgcn_mfma_f32_16x16x32_f16(kf, qreg[0], cinit, 0, 0, 0);
            float p0 = fast_exp2(s4[0]), p1 = fast_exp2(s4[1]);
            float p2 = fast_exp2(s4[2]), p3 = fast_exp2(s4[3]);
            union { f16x2 gp[2]; h4 v; } pu;
            pu.gp[0] = __builtin_amdgcn_cvt_pkrtz(p0, p1);
            pu.gp[1] = __builtin_amdgcn_cvt_pkrtz(p2, p3);
            o0_0 = __builtin_amdgcn_mfma_f32_16x16x16f16(pu.v, v0, o0_0, 0, 0, 0);
            o1_0 = __builtin_amdgcn_mfma_f32_16x16x16f16(pu.v, v1, o1_0, 0, 0, 0);
        }
        // qt1 chain
        {
            f4v s4 = __builtin_amdgcn_mfma_f32_16x16x32_f16(kf, qreg[1], cinit, 0, 0, 0);
            float p0 = fast_exp2(s4[0]), p1 = fast_exp2(s4[1]);
            float p2 = fast_exp2(s4[2]), p3 = fast_exp2(s4[3]);
            union { f16x2 gp[2]; h4 v; } pu;
            pu.gp[0] = __builtin_amdgcn_cvt_pkrtz(p0, p1);
            pu.gp[1] = __builtin_amdgcn_cvt_pkrtz(p2, p3);
            o0_1 = __builtin_amdgcn_mfma_f32_16x16x16f16(pu.v, v0, o0_1, 0, 0, 0);
            o1_1 = __builtin_amdgcn_mfma_f32_16x16x16f16(pu.v, v1, o1_1, 0, 0, 0);
        }
    }

    // pass-A epilogues (AO stores issue now; latency hides under pass B)
    attn_epilogue(o0_0, o1_0, Ob[wid][0], AOw, q0w,      lane, l15, g);
    attn_epilogue(o0_1, o1_1, Ob[wid][1], AOw, q0w + 16, lane, l15, g);

    // ---- PASS B: qt2 alone (a/b acc split for dep-breaking) ----
    f4v o0a = {}, o0b = {}, o1a = {}, o1b = {};
    #pragma unroll
    for (int mt = 0; mt < 24; ++mt) {
        h8 kf = *(const h8*)(Kh + (16 * mt + l15) * 36 + g * 8);
        h4 v0 = *(const h4*)(Vt + l15 * 388 + 16 * mt + 4 * g);
        h4 v1 = *(const h4*)(Vt + v1row * 388 + 16 * mt + 4 * g);
        const f4v cinit = {-46.f, -46.f, -46.f, -46.f};
        f4v s4 = __builtin_amdgcn_mfma_f32_16x16x32_f16(kf, qreg[2], cinit, 0, 0, 0);
        float p0 = fast_exp2(s4[0]), p1 = fast_exp2(s4[1]);
        float p2 = fast_exp2(s4[2]), p3 = fast_exp2(s4[3]);
        union { f16x2 gp[2]; h4 v; } pu;
        pu.gp[0] = __builtin_amdgcn_cvt_pkrtz(p0, p1);
        pu.gp[1] = __builtin_amdgcn_cvt_pkrtz(p2, p3);
        if (mt & 1) {
            o0b = __builtin_amdgcn_mfma_f32_16x16x16f16(pu.v, v0, o0b, 0, 0, 0);
            o1b = __builtin_amdgcn_mfma_f32_16x16x16f16(pu.v, v1, o1b, 0, 0, 0);
        } else {
            o0a = __builtin_amdgcn_mfma_f32_16x16x16f16(pu.v, v0, o0a, 0, 0, 0);
            o1a = __builtin_amdgcn_mfma_f32_16x16x16f16(pu.v, v1, o1a, 0, 0, 0);
        }
    }
    attn_epilogue(o0a + o0b, o1a + o1b, Ob[wid][0], AOw, q0w + 32, lane, l15, g);
}

// ---------------------------------------------------------------------------
// Kernel 4 (r23): FUSED projection + window-reverse + roll-back + transpose.
// Eliminates the PO staging round-trip (37.7MB write + 37.7MB read).
// Block = one (dd,hh) output row (grid 1536):
//  1. gather 64 rolled tokens' AO rows (8 heads x 48B) -> LDS Arows[64][200]
//     (AO just written by attn -> L2/L3-served scattered reads);
//  2. GEMM M=64 x N=192 x K=192: af[6] per wave from LDS, bf from Wb (L2),
//     acc[12] f4v (same MFMA count as the old proj in total);
//  3. acc -> tileT[192][68] f32 (ALIASES Arows' LDS; af are in registers
//     before the barrier) -> write out as full 256B (c, 64w) rows.
// LDS 52224B -> 2 blocks/CU even at a 128K usable limit.
// ---------------------------------------------------------------------------
__global__ __launch_bounds__(256) void proj_wb_kernel(
    const _Float16* __restrict__ AOs, const _Float16* __restrict__ Wb,
    const float* __restrict__ bias, float* __restrict__ out)
{
    const int bid = blockIdx.x;        // dd*64 + hh
    const int dd = bid >> 6;
    const int hh = bid & 63;
    const int tid = threadIdx.x;
    const int lane = tid & 63, wid = tid >> 6;
    const int l15 = lane & 15, g = lane >> 4;

    __shared__ __attribute__((aligned(16))) unsigned char lmem[192 * 68 * 4]; // 52224B
    _Float16* Arows = (_Float16*)lmem;   // [64][200] f16 (25600B), dead after af load
    float* tileT = (float*)lmem;         // [192][68] f32, lives after barrier

    // inverse roll: window-space coords for this output row
    int d_r = dd + 21; if (d_r >= 24) d_r -= 24;
    int h_r = hh + 60; if (h_r >= 64) h_r -= 64;
    const int wi = d_r / 6, td = d_r - wi * 6;
    const int hi = h_r >> 3, th = h_r & 7;
    const int winbase = (wi * 8 + hi) * 8;
    const int nbase = (td * 8 + th) * 8;

    // 1. gather AO rows: 1536 h8 chunks (64 tokens x 24), 6 per thread
    #pragma unroll
    for (int it = 0; it < 6; ++it) {
        int idx = it * 256 + tid;
        int t = idx / 24;              // token (= output w)
        int ch = idx - t * 24;         // 8-channel chunk 0..23
        int w_r = t + 60; if (w_r >= 64) w_r -= 64;
        int win = winbase + (w_r >> 3);
        int n = nbase + (w_r & 7);
        int head = ch / 3, sub = ch - 3 * head;
        h8 v = *(const h8*)(AOs + (size_t)(head * 256 + win) * 9216
                                + (size_t)n * 24 + sub * 8);
        *(h8*)(Arows + t * 200 + ch * 8) = v;
    }
    __syncthreads();

    // 2a. preload this wave's 6 A-fragments (tokens wid*16..+15) to REGISTERS
    h8 af[6];
    #pragma unroll
    for (int kk = 0; kk < 6; ++kk)
        af[kk] = *(const h8*)(Arows + (wid * 16 + l15) * 200 + kk * 32 + g * 8);
    __syncthreads();   // Arows dead; tileT may now overwrite lmem

    // 2b. GEMM: n-outer, kk-inner; lane (l15,g) j -> C[c=n*16+l15][tok=wid*16+4g+j]
    f4v acc[12];
    #pragma unroll
    for (int n = 0; n < 12; ++n) {
        f4v a = {};
        #pragma unroll
        for (int kk = 0; kk < 6; ++kk) {
            h8 bf = *(const h8*)(Wb + (size_t)(n * 16 + l15) * 192 + kk * 32 + g * 8);
            a = __builtin_amdgcn_mfma_f32_16x16x32_f16(af[kk], bf, a, 0, 0, 0);
        }
        acc[n] = a;
    }

    // 3a. bias + write tileT[c][tok] (pad 68 -> 16B-aligned f4v rows)
    #pragma unroll
    for (int n = 0; n < 12; ++n) {
        float b = bias[n * 16 + l15];
        f4v vv = acc[n];
        vv[0] += b; vv[1] += b; vv[2] += b; vv[3] += b;
        *(f4v*)(tileT + (n * 16 + l15) * 68 + wid * 16 + g * 4) = vv;
    }
    __syncthreads();

    // 3b. write out: full 256B (c, 64w) rows; 4 lanes cover 64B contiguous
    float* obase = out + (size_t)dd * 4096 + hh * 64;
    #pragma unroll
    for (int r = 0; r < 3; ++r) {
        const int c = r * 64 + (tid >> 2);
        float* orow = obase + (size_t)c * 98304;
        const float* trow = tileT + c * 68;
        #pragma unroll
        for (int q = 0; q < 4; ++q) {
            const int w0 = q * 16 + (tid & 3) * 4;
            f4v v = *(const f4v*)(trow + w0);
            *(f4v*)(orow + w0) = v;
        }
    }
}

// ---------------------------------------------------------------------------
extern "C" void kernel_launch(void* const* d_in, const int* in_sizes, int n_in,
                              void* d_out, int out_size, void* d_ws, size_t ws_size,
                              hipStream_t stream) {
    const float* q_map = (const float*)d_in[0];
    const float* k_map = (const float*)d_in[1];
    const float* v_map = (const float*)d_in[2];
    const float* nqw = (const float*)d_in[3];
    const float* nqb = (const float*)d_in[4];
    const float* nkw = (const float*)d_in[5];
    const float* nkb = (const float*)d_in[6];
    const float* pw = (const float*)d_in[7];
    const float* pb = (const float*)d_in[8];
    float* out = (float*)d_out;

    // workspace layout (f16): Qs, Ks, Vs, AOs each 8*256*384*24 = 18,874,368 elems
    _Float16* ws = (_Float16*)d_ws;
    const size_t BUF = (size_t)8 * 256 * 384 * 24;
    _Float16* Qs = ws;
    _Float16* Ks = ws + BUF;
    _Float16* Vs = ws + 2 * BUF;
    _Float16* AOs = ws + 3 * BUF;
    _Float16* Wb = ws + 4 * BUF;   // + 73728 B, total ~151 MB

    ln_stage_kernel<<<dim3(768, 3), 256, 0, stream>>>(q_map, k_map, v_map,
                                                      nqw, nqb, nkw, nkb, Qs, Ks, Vs);
    wconv_kernel<<<144, 256, 0, stream>>>(pw, Wb);
    attn_kernel<<<dim3(256, 8), 512, 0, stream>>>(Qs, Ks, Vs, AOs);
    proj_wb_kernel<<<1536, 256, 0, stream>>>(AOs, Wb, pb, out);
}

// Round 24
// 191.724 us; speedup vs baseline: 1.0960x; 1.0146x over previous
//
#include <hip/hip_runtime.h>

typedef float f4v __attribute__((ext_vector_type(4)));
typedef _Float16 h8 __attribute__((ext_vector_type(8)));
typedef _Float16 h4 __attribute__((ext_vector_type(4)));
typedef _Float16 h2 __attribute__((ext_vector_type(2)));
typedef __fp16 f16x2 __attribute__((ext_vector_type(2)));

// Problem constants
// C=192, NH=8, DH=24, window 6x8x8 -> N=384 tokens, D/H/W = 24/64/64 -> 256 windows
// shift (3,4,4). Spatial stride per channel = 24*64*64 = 98304.
// Staging layout (f16): [head][win][n][24]  -> slab (head,win) = 384*24 = 9216 elems.

__device__ __forceinline__ float fast_exp2(float x) {
#if __has_builtin(__builtin_amdgcn_exp2f)
    return __builtin_amdgcn_exp2f(x);
#else
    return exp2f(x);
#endif
}
__device__ __forceinline__ float fast_rcp(float x) {
#if __has_builtin(__builtin_amdgcn_rcpf)
    return __builtin_amdgcn_rcpf(x);
#else
    return 1.0f / x;
#endif
}

// region slot for token n (3-bit: d,h,w boundary crossing), block-uniform wi/hi/wj
__device__ __forceinline__ int region_slot(int n, int wi, int hi, int wj) {
    int s = 0;
    if (wi == 3 && (n >> 6) >= 3) s += 4;
    if (hi == 7 && ((n >> 3) & 7) >= 4) s += 2;
    if (wj == 7 && (n & 7) >= 4) s += 1;
    return s;
}

// ---------------------------------------------------------------------------
// Kernel 1 (r24): PERSISTENT double-buffered LN staging.
// Theory: all previous ln forms were launch-generation LOCKSTEPPED — blocks
// execute phases in global sync, so HBM reads idle during LDS/write phases
// (explains r18/r20/r21/r22 nulls: occupancy/MLP/conflicts/granule all
// orthogonal to duty cycle). Fix: 512 persistent blocks (2/CU, all resident),
// 9 slices each, double-buffered tile; next slice's 12 loads issued BETWEEN
// stats and phase 3 -> reads overlap normalize/write. Slices iterate with
// stride 512 so the resident set is a contiguous window; tensor is uniform
// per iteration (i/3); sgam/sbet reloaded at tensor boundaries (guarded).
// ---------------------------------------------------------------------------
__global__ __launch_bounds__(256) void ln_stage_kernel(
    const float* __restrict__ q, const float* __restrict__ k, const float* __restrict__ v,
    const float* __restrict__ nqw, const float* __restrict__ nqb,
    const float* __restrict__ nkw, const float* __restrict__ nkb,
    _Float16* __restrict__ Qs, _Float16* __restrict__ Ks, _Float16* __restrict__ Vs)
{
    const int tid = threadIdx.x;
    const int bid = blockIdx.x;      // 0..511

    __shared__ __attribute__((aligned(16))) _Float16 tile[2][192][70];
    __shared__ __attribute__((aligned(16))) float psum4[4][64];
    __shared__ __attribute__((aligned(16))) float psq4[4][64];
    __shared__ float smean[64];
    __shared__ float srstd[64];
    __shared__ float sgam[192];
    __shared__ float sbet[192];

    const int lane = tid & 63;
    const int wid = tid >> 6;
    const int c0 = tid >> 4;           // 0..15
    const int col = (tid & 15) << 2;   // 0..60
    const float qscale = 0.20412414523193154f * 1.44269504088896340f;

    // prologue: tensor 0 norm params + slice 0 loads
    if (tid < 192) { sgam[tid] = nqw[tid]; sbet[tid] = nqb[tid]; }
    f4v xr[12];
    {
        const int d = bid >> 6, h = bid & 63;
        const float* base = q + (size_t)d * 4096 + (size_t)h * 64 + col;
        #pragma unroll
        for (int r = 0; r < 12; ++r)
            xr[r] = *(const f4v*)(base + (size_t)(r * 16 + c0) * 98304);
    }

    for (int i = 0; i < 9; ++i) {
        const int gs = i * 512 + bid;
        const int tensor = i / 3;                    // uniform per iteration
        const int s = gs - tensor * 1536;
        const int d = s >> 6, h = s & 63;
        const int cur = i & 1;
        _Float16* dst = (tensor == 0) ? Qs : (tensor == 1) ? Ks : Vs;
        const float scale = (tensor == 0) ? qscale : 1.0f;

        // tensor boundary: reload norm params (barrier guards prev phase-3 reads)
        if (i == 3 || i == 6) {
            __syncthreads();
            if (tid < 192) { sgam[tid] = nkw[tid]; sbet[tid] = nkb[tid]; }
        }

        // phase 1b: partials (f32, from regs) + f16 tile[cur]
        {
            f4v s4 = {}, ss4 = {};
            #pragma unroll
            for (int r = 0; r < 12; ++r) {
                f4v x = xr[r];
                s4 += x;
                ss4 += x * x;
                h4 hx;
                hx[0] = (_Float16)x[0]; hx[1] = (_Float16)x[1];
                hx[2] = (_Float16)x[2]; hx[3] = (_Float16)x[3];
                *(h4*)&tile[cur][r * 16 + c0][col] = hx;
            }
            #pragma unroll
            for (int m = 0; m < 4; ++m) {
                s4[m] += __shfl_xor(s4[m], 16);  s4[m] += __shfl_xor(s4[m], 32);
                ss4[m] += __shfl_xor(ss4[m], 16); ss4[m] += __shfl_xor(ss4[m], 32);
            }
            if (lane < 16) {
                *(f4v*)&psum4[wid][lane * 4] = s4;
                *(f4v*)&psq4[wid][lane * 4] = ss4;
            }
        }
        __syncthreads();

        // phase 2: per-token stats
        if (tid < 64) {
            float S = psum4[0][tid] + psum4[1][tid] + psum4[2][tid] + psum4[3][tid];
            float SS = psq4[0][tid] + psq4[1][tid] + psq4[2][tid] + psq4[3][tid];
            float mean = S * (1.0f / 192.0f);
            float var = SS * (1.0f / 192.0f) - mean * mean;
            smean[tid] = mean;
            srstd[tid] = rsqrtf(var + 1e-5f);
        }

        // prefetch next slice's loads NOW (overlap with phase 3's LDS+writes)
        if (i < 8) {
            const int gs2 = gs + 512;
            const int t2 = (i + 1) / 3;
            const int s2 = gs2 - t2 * 1536;
            const int d2 = s2 >> 6, h2 = s2 & 63;
            const float* src2 = (t2 == 0) ? q : (t2 == 1) ? k : v;
            const float* base2 = src2 + (size_t)d2 * 4096 + (size_t)h2 * 64 + col;
            #pragma unroll
            for (int r = 0; r < 12; ++r)
                xr[r] = *(const f4v*)(base2 + (size_t)(r * 16 + c0) * 98304);
        }
        __syncthreads();

        // phase 3: normalize from tile[cur] + write f16 staging [head][win][n][24]
        {
            const int wpos = tid >> 2;   // 0..63 source w
            const int p = tid & 3;       // channel quarter = heads 2p, 2p+1
            const float mean = smean[wpos];
            const float rstd = srstd[wpos];
            int d_r = d + 21; if (d_r >= 24) d_r -= 24;
            int h_r = h + 60; if (h_r >= 64) h_r -= 64;
            int w_r = wpos + 60; if (w_r >= 64) w_r -= 64;
            const int wi = d_r / 6, td = d_r - wi * 6;
            const int hi = h_r >> 3, th = h_r & 7;
            const int wj = w_r >> 3, tw = w_r & 7;
            const int win = (wi * 8 + hi) * 8 + wj;
            const int n = (td * 8 + th) * 8 + tw;
            #pragma unroll
            for (int hh2 = 0; hh2 < 2; ++hh2) {
                const int head = p * 2 + hh2;
                _Float16* outp = dst + (size_t)(head * 256 + win) * 9216 + n * 24;
                #pragma unroll
                for (int cc = 0; cc < 3; ++cc) {
                    const int c = head * 24 + cc * 8;
                    h8 hv;
                    #pragma unroll
                    for (int j = 0; j < 8; ++j) {
                        float x = ((float)tile[cur][c + j][wpos] - mean) * rstd * sgam[c + j] + sbet[c + j];
                        hv[j] = (_Float16)(x * scale);
                    }
                    *(h8*)(outp + cc * 8) = hv;
                }
            }
        }
    }
}

// ---------------------------------------------------------------------------
// Kernel 2: proj_w f32 -> f16
// ---------------------------------------------------------------------------
__global__ __launch_bounds__(256) void wconv_kernel(const float* __restrict__ w,
                                                    _Float16* __restrict__ wb)
{
    int i = blockIdx.x * 256 + threadIdx.x;
    if (i < 192 * 192) wb[i] = (_Float16)w[i];
}

// ---------------------------------------------------------------------------
// attn epilogue: rowsum comes FREE from o1's duplicate lanes (l15>=8 read the
// ones-row) -> inv via one shfl per j. Wave-private Ob sub-tile; per-wave DS
// ordering + lgkmcnt fence (proven r4+).
// ---------------------------------------------------------------------------
__device__ __forceinline__ void attn_epilogue(
    f4v o0, f4v o1, _Float16* __restrict__ Op,
    _Float16* __restrict__ AOw, int q0, int lane, int l15, int g)
{
    #pragma unroll
    for (int j = 0; j < 4; ++j) {
        float rs = __shfl(o1[j], (g << 4) | 8);   // lane l15=8 of this g holds rowsum
        float inv = fast_rcp(rs);
        const int r = 4 * g + j;
        Op[r * 24 + l15] = (_Float16)(o0[j] * inv);
        if (l15 < 8) Op[r * 24 + 16 + l15] = (_Float16)(o1[j] * inv);
    }
    asm volatile("s_waitcnt lgkmcnt(0)" ::: "memory");
    // coalesced 768B burst: 48 lanes x 16B contiguous
    if (lane < 48) {
        h8 ov = *(const h8*)(Op + lane * 8);
        *(h8*)(AOw + (size_t)q0 * 24 + lane * 8) = ov;
    }
    asm volatile("" ::: "memory");
}

// ---------------------------------------------------------------------------
// Kernel 3: windowed attention, one block per (window, head). 8 WAVES (512t).
// r17 structure (unchanged): region-channel masking in the K=32 pad (one-hot
// * sqrt(40), cinit -46 -> masked p == 0 in f16); rowsum via ones-row in o1's
// duplicate lanes; 2+1 split fusion (pass A fuses qt{0,1}, pass B = qt2,
// pass-A AO stores hide under pass B). VGPR ~124 at (512,2) — do not perturb.
// ---------------------------------------------------------------------------
__global__ __launch_bounds__(512, 2) void attn_kernel(
    const _Float16* __restrict__ Qs, const _Float16* __restrict__ Ks,
    const _Float16* __restrict__ Vs, _Float16* __restrict__ AOs)
{
    const int win = blockIdx.x;
    const int head = blockIdx.y;
    const int tid = threadIdx.x;
    const int lane = tid & 63;
    const int wid = tid >> 6;        // 0..7
    const int l15 = lane & 15;
    const int g = lane >> 4;

    __shared__ __attribute__((aligned(16))) _Float16 Kh[384 * 36];      // [token][36]: dh0..23, onehot 24..31, pad
    __shared__ __attribute__((aligned(16))) _Float16 Vt[25 * 388];      // [dh][token pad388]; row 24 = ones
    __shared__ __attribute__((aligned(16))) _Float16 Ob[8][2][16 * 24]; // per-wave, qt-parity dbuf

    const int wi = win >> 6, hi = (win >> 3) & 7, wj = win & 7;

    const size_t slab = (size_t)(head * 256 + win) * 9216;
    const _Float16* Kw = Ks + slab;
    const _Float16* Vw = Vs + slab;
    const _Float16* Qw = Qs + slab;
    _Float16* AOw = AOs + slab;

    const _Float16 mreg = (_Float16)6.32455532f;   // sqrt(40)

    // ---- hoist this wave's 3 Q fragments; g==3 = one-hot(region(q)) * m ----
    h8 qreg[3];
    #pragma unroll
    for (int qt = 0; qt < 3; ++qt) {
        h8 z = {};
        if (g < 3) {
            z = *(const h8*)(Qw + (size_t)(wid * 48 + qt * 16 + l15) * 24 + g * 8);
        } else {
            int slot = region_slot(wid * 48 + qt * 16 + l15, wi, hi, wj);
            #pragma unroll
            for (int j = 0; j < 8; ++j) z[j] = (slot == j) ? mreg : (_Float16)0.f;
        }
        qreg[qt] = z;
    }

    // ---- stage K (36-wide rows + one-hot tails), V^T, ones-row ----
    {
        const h8* K8 = (const h8*)Kw;
        const h8* V8 = (const h8*)Vw;
        #pragma unroll
        for (int it = 0; it < 5; ++it) {
            int idx = it * 512 + tid;        // 0..2303 ; 0..1151 = K, 1152.. = V
            if (idx < 1152) {
                int n = idx / 3;
                int ch = idx - n * 3;
                *(h8*)(Kh + n * 36 + ch * 8) = K8[idx];
            } else if (idx < 2304) {
                int i = idx - 1152;          // flat h8 index in V slab
                int n = i / 3;               // token
                int ch = i - n * 3;          // 8-dh chunk
                h8 vv = V8[i];
                #pragma unroll
                for (int j = 0; j < 8; ++j) Vt[(ch * 8 + j) * 388 + n] = vv[j];
            }
        }
        if (tid < 384) {
            int slot = region_slot(tid, wi, hi, wj);
            h8 t;
            #pragma unroll
            for (int j = 0; j < 8; ++j) t[j] = (slot == j) ? mreg : (_Float16)0.f;
            *(h8*)(Kh + tid * 36 + 24) = t;
            Vt[24 * 388 + tid] = (_Float16)1.f;   // ones-row for rowsum
        }
    }
    __syncthreads();

    // lanes 0-7 of o1 -> dh 16-23; lanes 8-15 -> ones row (rowsum)
    const int v1row = (l15 < 8) ? (16 + l15) : 24;
    const int q0w = wid * 48;

    // ---- PASS A: fused qt0+qt1 mt loop (shared kf/v0/v1; 2 chains) ----
    f4v o0_0 = {}, o1_0 = {}, o0_1 = {}, o1_1 = {};
    #pragma unroll
    for (int mt = 0; mt < 24; ++mt) {
        h8 kf = *(const h8*)(Kh + (16 * mt + l15) * 36 + g * 8);
        h4 v0 = *(const h4*)(Vt + l15 * 388 + 16 * mt + 4 * g);
        h4 v1 = *(const h4*)(Vt + v1row * 388 + 16 * mt + 4 * g);
        const f4v cinit = {-46.f, -46.f, -46.f, -46.f};

        // qt0 chain
        {
            f4v s4 = __builtin_amdgcn_mfma_f32_16x16x32_f16(kf, qreg[0], cinit, 0, 0, 0);
            float p0 = fast_exp2(s4[0]), p1 = fast_exp2(s4[1]);
            float p2 = fast_exp2(s4[2]), p3 = fast_exp2(s4[3]);
            union { f16x2 gp[2]; h4 v; } pu;
            pu.gp[0] = __builtin_amdgcn_cvt_pkrtz(p0, p1);
            pu.gp[1] = __builtin_amdgcn_cvt_pkrtz(p2, p3);
            o0_0 = __builtin_amdgcn_mfma_f32_16x16x16f16(pu.v, v0, o0_0, 0, 0, 0);
            o1_0 = __builtin_amdgcn_mfma_f32_16x16x16f16(pu.v, v1, o1_0, 0, 0, 0);
        }
        // qt1 chain
        {
            f4v s4 = __builtin_amdgcn_mfma_f32_16x16x32_f16(kf, qreg[1], cinit, 0, 0, 0);
            float p0 = fast_exp2(s4[0]), p1 = fast_exp2(s4[1]);
            float p2 = fast_exp2(s4[2]), p3 = fast_exp2(s4[3]);
            union { f16x2 gp[2]; h4 v; } pu;
            pu.gp[0] = __builtin_amdgcn_cvt_pkrtz(p0, p1);
            pu.gp[1] = __builtin_amdgcn_cvt_pkrtz(p2, p3);
            o0_1 = __builtin_amdgcn_mfma_f32_16x16x16f16(pu.v, v0, o0_1, 0, 0, 0);
            o1_1 = __builtin_amdgcn_mfma_f32_16x16x16f16(pu.v, v1, o1_1, 0, 0, 0);
        }
    }

    // pass-A epilogues (AO stores issue now; latency hides under pass B)
    attn_epilogue(o0_0, o1_0, Ob[wid][0], AOw, q0w,      lane, l15, g);
    attn_epilogue(o0_1, o1_1, Ob[wid][1], AOw, q0w + 16, lane, l15, g);

    // ---- PASS B: qt2 alone (a/b acc split for dep-breaking) ----
    f4v o0a = {}, o0b = {}, o1a = {}, o1b = {};
    #pragma unroll
    for (int mt = 0; mt < 24; ++mt) {
        h8 kf = *(const h8*)(Kh + (16 * mt + l15) * 36 + g * 8);
        h4 v0 = *(const h4*)(Vt + l15 * 388 + 16 * mt + 4 * g);
        h4 v1 = *(const h4*)(Vt + v1row * 388 + 16 * mt + 4 * g);
        const f4v cinit = {-46.f, -46.f, -46.f, -46.f};
        f4v s4 = __builtin_amdgcn_mfma_f32_16x16x32_f16(kf, qreg[2], cinit, 0, 0, 0);
        float p0 = fast_exp2(s4[0]), p1 = fast_exp2(s4[1]);
        float p2 = fast_exp2(s4[2]), p3 = fast_exp2(s4[3]);
        union { f16x2 gp[2]; h4 v; } pu;
        pu.gp[0] = __builtin_amdgcn_cvt_pkrtz(p0, p1);
        pu.gp[1] = __builtin_amdgcn_cvt_pkrtz(p2, p3);
        if (mt & 1) {
            o0b = __builtin_amdgcn_mfma_f32_16x16x16f16(pu.v, v0, o0b, 0, 0, 0);
            o1b = __builtin_amdgcn_mfma_f32_16x16x16f16(pu.v, v1, o1b, 0, 0, 0);
        } else {
            o0a = __builtin_amdgcn_mfma_f32_16x16x16f16(pu.v, v0, o0a, 0, 0, 0);
            o1a = __builtin_amdgcn_mfma_f32_16x16x16f16(pu.v, v1, o1a, 0, 0, 0);
        }
    }
    attn_epilogue(o0a + o0b, o1a + o1b, Ob[wid][0], AOw, q0w + 32, lane, l15, g);
}

// ---------------------------------------------------------------------------
// Kernel 4: FUSED projection + window-reverse + roll-back + transpose (r23).
// Block = one (dd,hh) output row (grid 1536): gather rolled AO rows -> LDS,
// GEMM 64x192x192 (af from LDS regs, bf from Wb), acc -> tileT (aliased LDS)
// -> full 256B (c, 64w) row writes. LDS 52224B.
// ---------------------------------------------------------------------------
__global__ __launch_bounds__(256) void proj_wb_kernel(
    const _Float16* __restrict__ AOs, const _Float16* __restrict__ Wb,
    const float* __restrict__ bias, float* __restrict__ out)
{
    const int bid = blockIdx.x;        // dd*64 + hh
    const int dd = bid >> 6;
    const int hh = bid & 63;
    const int tid = threadIdx.x;
    const int lane = tid & 63, wid = tid >> 6;
    const int l15 = lane & 15, g = lane >> 4;

    __shared__ __attribute__((aligned(16))) unsigned char lmem[192 * 68 * 4]; // 52224B
    _Float16* Arows = (_Float16*)lmem;   // [64][200] f16 (25600B), dead after af load
    float* tileT = (float*)lmem;         // [192][68] f32, lives after barrier

    // inverse roll: window-space coords for this output row
    int d_r = dd + 21; if (d_r >= 24) d_r -= 24;
    int h_r = hh + 60; if (h_r >= 64) h_r -= 64;
    const int wi = d_r / 6, td = d_r - wi * 6;
    const int hi = h_r >> 3, th = h_r & 7;
    const int winbase = (wi * 8 + hi) * 8;
    const int nbase = (td * 8 + th) * 8;

    // 1. gather AO rows: 1536 h8 chunks (64 tokens x 24), 6 per thread
    #pragma unroll
    for (int it = 0; it < 6; ++it) {
        int idx = it * 256 + tid;
        int t = idx / 24;              // token (= output w)
        int ch = idx - t * 24;         // 8-channel chunk 0..23
        int w_r = t + 60; if (w_r >= 64) w_r -= 64;
        int win = winbase + (w_r >> 3);
        int n = nbase + (w_r & 7);
        int head = ch / 3, sub = ch - 3 * head;
        h8 v = *(const h8*)(AOs + (size_t)(head * 256 + win) * 9216
                                + (size_t)n * 24 + sub * 8);
        *(h8*)(Arows + t * 200 + ch * 8) = v;
    }
    __syncthreads();

    // 2a. preload this wave's 6 A-fragments (tokens wid*16..+15) to REGISTERS
    h8 af[6];
    #pragma unroll
    for (int kk = 0; kk < 6; ++kk)
        af[kk] = *(const h8*)(Arows + (wid * 16 + l15) * 200 + kk * 32 + g * 8);
    __syncthreads();   // Arows dead; tileT may now overwrite lmem

    // 2b. GEMM: n-outer, kk-inner; lane (l15,g) j -> C[c=n*16+l15][tok=wid*16+4g+j]
    f4v acc[12];
    #pragma unroll
    for (int n = 0; n < 12; ++n) {
        f4v a = {};
        #pragma unroll
        for (int kk = 0; kk < 6; ++kk) {
            h8 bf = *(const h8*)(Wb + (size_t)(n * 16 + l15) * 192 + kk * 32 + g * 8);
            a = __builtin_amdgcn_mfma_f32_16x16x32_f16(af[kk], bf, a, 0, 0, 0);
        }
        acc[n] = a;
    }

    // 3a. bias + write tileT[c][tok] (pad 68 -> 16B-aligned f4v rows)
    #pragma unroll
    for (int n = 0; n < 12; ++n) {
        float b = bias[n * 16 + l15];
        f4v vv = acc[n];
        vv[0] += b; vv[1] += b; vv[2] += b; vv[3] += b;
        *(f4v*)(tileT + (n * 16 + l15) * 68 + wid * 16 + g * 4) = vv;
    }
    __syncthreads();

    // 3b. write out: full 256B (c, 64w) rows; 4 lanes cover 64B contiguous
    float* obase = out + (size_t)dd * 4096 + hh * 64;
    #pragma unroll
    for (int r = 0; r < 3; ++r) {
        const int c = r * 64 + (tid >> 2);
        float* orow = obase + (size_t)c * 98304;
        const float* trow = tileT + c * 68;
        #pragma unroll
        for (int q = 0; q < 4; ++q) {
            const int w0 = q * 16 + (tid & 3) * 4;
            f4v v = *(const f4v*)(trow + w0);
            *(f4v*)(orow + w0) = v;
        }
    }
}

// ---------------------------------------------------------------------------
extern "C" void kernel_launch(void* const* d_in, const int* in_sizes, int n_in,
                              void* d_out, int out_size, void* d_ws, size_t ws_size,
                              hipStream_t stream) {
    const float* q_map = (const float*)d_in[0];
    const float* k_map = (const float*)d_in[1];
    const float* v_map = (const float*)d_in[2];
    const float* nqw = (const float*)d_in[3];
    const float* nqb = (const float*)d_in[4];
    const float* nkw = (const float*)d_in[5];
    const float* nkb = (const float*)d_in[6];
    const float* pw = (const float*)d_in[7];
    const float* pb = (const float*)d_in[8];
    float* out = (float*)d_out;

    // workspace layout (f16): Qs, Ks, Vs, AOs each 8*256*384*24 = 18,874,368 elems
    _Float16* ws = (_Float16*)d_ws;
    const size_t BUF = (size_t)8 * 256 * 384 * 24;
    _Float16* Qs = ws;
    _Float16* Ks = ws + BUF;
    _Float16* Vs = ws + 2 * BUF;
    _Float16* AOs = ws + 3 * BUF;
    _Float16* Wb = ws + 4 * BUF;   // + 73728 B, total ~151 MB

    ln_stage_kernel<<<512, 256, 0, stream>>>(q_map, k_map, v_map,
                                             nqw, nqb, nkw, nkb, Qs, Ks, Vs);
    wconv_kernel<<<144, 256, 0, stream>>>(pw, Wb);
    attn_kernel<<<dim3(256, 8), 512, 0, stream>>>(Qs, Ks, Vs, AOs);
    proj_wb_kernel<<<1536, 256, 0, stream>>>(AOs, Wb, pb, out);
}